// Round 2
// baseline (181.914 us; speedup 1.0000x reference)
//
#include <hip/hip_runtime.h>
#include <hip/hip_bf16.h>

// loss = (1/N) * [ sum_i softplus(-s_ii) + sum_{i!=j} softplus(s_ij) ] + ln2
// where S = E E^T, N=16384, D=128.
// Triangular 128x128 MFMA tiles (off-diagonal weight 2), fused stable-softplus
// epilogue, one atomicAdd per block, tiny finalize kernel.
// ws_size-guarded: fast path casts E->bf16 in d_ws (4 MiB); fallback stages
// fp32 directly and converts in-register (needs only 4 B of d_ws).

#define N_DOCS 16384
#define DIM 128
#define NTILE 128  // N_DOCS / 128

typedef __attribute__((ext_vector_type(8))) __bf16 bf16x8;
typedef __attribute__((ext_vector_type(4))) float f32x4;

typedef const __attribute__((address_space(1))) unsigned char* gptr_t;
typedef __attribute__((address_space(3))) unsigned char* lptr_t;

__device__ __forceinline__ unsigned short f2bf(float f) {
  unsigned int u = __float_as_uint(f);
  u += 0x7fffu + ((u >> 16) & 1u);  // round-to-nearest-even
  return (unsigned short)(u >> 16);
}

__global__ void cast_kernel(const float* __restrict__ in, unsigned short* __restrict__ out) {
  int i = blockIdx.x * blockDim.x + threadIdx.x;  // [0, 524288/4), exact
  float4 v = reinterpret_cast<const float4*>(in)[i];
  ushort4 o;
  o.x = f2bf(v.x); o.y = f2bf(v.y); o.z = f2bf(v.z); o.w = f2bf(v.w);
  reinterpret_cast<ushort4*>(out)[i] = o;
}

// Swizzle involution (T2 / rule #21): physical LDS byte p holds global byte
// p ^ (((p>>8)&7)<<4); reads of logical byte L use L ^ (((L>>8)&7)<<4).
// XOR touches bits 4..6 only, row bits (>=8) unaffected -> involution holds.

template <bool FROM_BF16>
__global__ __launch_bounds__(256, 2) void loss_kernel(const void* __restrict__ src,
                                                      float* __restrict__ accum) {
  const int tc = blockIdx.x, tr = blockIdx.y;
  if (tr > tc) return;  // tile (tr,tc), tr<tc counted twice by symmetry

  __shared__ alignas(16) unsigned short As[128 * 128];  // 32 KiB, [row][k] bf16
  __shared__ alignas(16) unsigned short Bs[128 * 128];  // 32 KiB
  const int tid = threadIdx.x;

  if constexpr (FROM_BF16) {
    // 128-row slab = contiguous 32 KiB; linear LDS dest + pre-swizzled source.
    const unsigned char* srcA = (const unsigned char*)src + (size_t)tr * 32768;
    const unsigned char* srcB = (const unsigned char*)src + (size_t)tc * 32768;
#pragma unroll
    for (int it = 0; it < 8; ++it) {
      int p = (it * 256 + tid) * 16;
      int g = p ^ (((p >> 8) & 7) << 4);
      __builtin_amdgcn_global_load_lds((gptr_t)(srcA + g),
                                       (lptr_t)((unsigned char*)As + p), 16, 0, 0);
      __builtin_amdgcn_global_load_lds((gptr_t)(srcB + g),
                                       (lptr_t)((unsigned char*)Bs + p), 16, 0, 0);
    }
  } else {
    // fp32 direct: load float4, convert to 4 bf16 (8 B), ds_write swizzled.
    const float4* srcA4 = (const float4*)((const float*)src + (size_t)tr * 128 * 128);
    const float4* srcB4 = (const float4*)((const float*)src + (size_t)tc * 128 * 128);
#pragma unroll
    for (int it = 0; it < 16; ++it) {
      int idx = it * 256 + tid;             // float4 index within slab [0,4096)
      int L = idx * 8;                      // bf16 linear byte offset
      int swz = L ^ (((L >> 8) & 7) << 4);
      float4 a = srcA4[idx];
      ushort4 oa = {f2bf(a.x), f2bf(a.y), f2bf(a.z), f2bf(a.w)};
      *reinterpret_cast<ushort4*>((unsigned char*)As + swz) = oa;
      float4 b = srcB4[idx];
      ushort4 ob = {f2bf(b.x), f2bf(b.y), f2bf(b.z), f2bf(b.w)};
      *reinterpret_cast<ushort4*>((unsigned char*)Bs + swz) = ob;
    }
  }
  __syncthreads();

  const int wid = tid >> 6;
  const int lane = tid & 63;
  const int wm = wid >> 1, wn = wid & 1;  // 2x2 waves, each owns 64x64
  const int lrow = lane & 15;             // A-row / B-col within fragment
  const int kgrp = lane >> 4;             // 8-elem k-group

  f32x4 acc[4][4];
#pragma unroll
  for (int a = 0; a < 4; ++a)
#pragma unroll
    for (int b = 0; b < 4; ++b) acc[a][b] = (f32x4){0.f, 0.f, 0.f, 0.f};

#pragma unroll
  for (int ks = 0; ks < 4; ++ks) {  // K = 128 = 4 * 32
    bf16x8 af[4], bfr[4];
#pragma unroll
    for (int f = 0; f < 4; ++f) {
      int ar = wm * 64 + f * 16 + lrow;
      int ab = (ar * 256 + ks * 64 + kgrp * 16) ^ ((ar & 7) << 4);
      af[f] = *reinterpret_cast<const bf16x8*>((const unsigned char*)As + ab);
      int br = wn * 64 + f * 16 + lrow;
      int bb = (br * 256 + ks * 64 + kgrp * 16) ^ ((br & 7) << 4);
      bfr[f] = *reinterpret_cast<const bf16x8*>((const unsigned char*)Bs + bb);
    }
#pragma unroll
    for (int fm = 0; fm < 4; ++fm)
#pragma unroll
      for (int fn = 0; fn < 4; ++fn)
        acc[fm][fn] = __builtin_amdgcn_mfma_f32_16x16x32_bf16(af[fm], bfr[fn], acc[fm][fn], 0, 0, 0);
  }

  // Epilogue: stable softplus(v) = max(v,0) + log(1+exp(-|v|)); diagonal
  // elements of diagonal tiles use v = -s_ii (positive-loss term).
  // C/D layout (16x16x32): col = lane&15, row = (lane>>4)*4 + reg.
  float lsum = 0.f;
  const bool diag = (tr == tc);
#pragma unroll
  for (int fm = 0; fm < 4; ++fm)
#pragma unroll
    for (int fn = 0; fn < 4; ++fn)
#pragma unroll
      for (int r = 0; r < 4; ++r) {
        float v = acc[fm][fn][r];
        if (diag) {
          int il = wm * 64 + fm * 16 + kgrp * 4 + r;
          int jl = wn * 64 + fn * 16 + lrow;
          if (il == jl) v = -v;
        }
        lsum += fmaxf(v, 0.f) + __logf(1.f + __expf(-fabsf(v)));
      }
  if (!diag) lsum *= 2.f;  // symmetric twin tile

#pragma unroll
  for (int off = 32; off > 0; off >>= 1) lsum += __shfl_down(lsum, off);

  __syncthreads();  // all fragment reads done before reusing As as scratch
  float* red = reinterpret_cast<float*>(As);
  if (lane == 0) red[wid] = lsum;
  __syncthreads();
  if (tid == 0) atomicAdd(accum, red[0] + red[1] + red[2] + red[3]);
}

__global__ void finalize_kernel(const float* __restrict__ accum, float* __restrict__ out) {
  out[0] = accum[0] * (1.0f / (float)N_DOCS) + 0.69314718055994531f;  // + ln2
}

extern "C" void kernel_launch(void* const* d_in, const int* in_sizes, int n_in,
                              void* d_out, int out_size, void* d_ws, size_t ws_size,
                              hipStream_t stream) {
  const float* E = (const float*)d_in[0];
  float* out = (float*)d_out;
  float* accum = (float*)d_ws;  // 4 B, always present

  hipMemsetAsync(accum, 0, sizeof(float), stream);
  dim3 grid(NTILE, NTILE);

  const size_t need = 256 + (size_t)N_DOCS * DIM * sizeof(unsigned short);  // 4 MiB + pad
  if (ws_size >= need) {
    unsigned short* ebf = (unsigned short*)((char*)d_ws + 256);
    cast_kernel<<<(N_DOCS * DIM / 4) / 256, 256, 0, stream>>>(E, ebf);
    loss_kernel<true><<<grid, 256, 0, stream>>>(ebf, accum);
  } else {
    loss_kernel<false><<<grid, 256, 0, stream>>>(E, accum);
  }
  finalize_kernel<<<1, 1, 0, stream>>>(accum, out);
}

// Round 6
// 173.325 us; speedup vs baseline: 1.0496x; 1.0496x over previous
//
#include <hip/hip_runtime.h>
#include <hip/hip_bf16.h>

// loss = (1/N) * [ sum_i softplus(-s_ii) + sum_{i!=j} softplus(s_ij) ] + ln2
// S = E E^T, N=16384, D=128.
// E is pre-scaled by sqrt(log2e) during the bf16 cast, so MFMA produces
// s' = s*log2e and softplus reduces to ln2*(max(s',0) + log2(1+2^-|s'|)),
// with the log2 term approximated by a cubic minimax poly u*P(u), u=2^-|s'|
// (|err| <= 0.0044 log2-units; worst-case loss error ~80 << 1495 threshold).
// Triangular tile grid (8256 blocks), 512 threads (8 waves, 2x4), 128x128
// tiles, K=128 resident in LDS, fused epilogue, 1 atomic per block.

#define N_DOCS 16384
#define DIM 128
#define NTILE 128          // N_DOCS / 128
#define NTRI (NTILE * (NTILE + 1) / 2)  // 8256

typedef __attribute__((ext_vector_type(8))) __bf16 bf16x8;
typedef __attribute__((ext_vector_type(4))) float f32x4;

typedef const __attribute__((address_space(1))) unsigned char* gptr_t;
typedef __attribute__((address_space(3))) unsigned char* lptr_t;

#define SQRT_LOG2E 1.2011224087864498f
#define LN2F 0.6931471805599453f
// log2(1+u) ~= u*(C0 + C1*u + C2*u^2) on u in [0,1]
#define PC0 1.43500f
#define PC1 (-0.62967f)
#define PC2 0.19907f

// 2^x -> v_exp_f32. Avoid glibc-colliding __exp2f; guard builtin spelling.
#if __has_builtin(__builtin_amdgcn_exp2f)
#define EXP2F(x) __builtin_amdgcn_exp2f(x)
#else
#define EXP2F(x) exp2f(x)
#endif

__device__ __forceinline__ unsigned short f2bf(float f) {
  unsigned int u = __float_as_uint(f);
  u += 0x7fffu + ((u >> 16) & 1u);  // round-to-nearest-even
  return (unsigned short)(u >> 16);
}

__global__ void cast_kernel(const float* __restrict__ in, unsigned short* __restrict__ out,
                            float* __restrict__ accum) {
  int i = blockIdx.x * blockDim.x + threadIdx.x;
  if (i == 0) accum[0] = 0.f;  // completes before loss_kernel (stream order)
  float4 v = reinterpret_cast<const float4*>(in)[i];
  ushort4 o;
  o.x = f2bf(v.x * SQRT_LOG2E); o.y = f2bf(v.y * SQRT_LOG2E);
  o.z = f2bf(v.z * SQRT_LOG2E); o.w = f2bf(v.w * SQRT_LOG2E);
  reinterpret_cast<ushort4*>(out)[i] = o;
}

// Swizzle involution (T2 / rule #21): physical LDS byte p holds logical byte
// p ^ (((p>>8)&7)<<4); read side applies the same XOR. Bits 4..6 only.

template <bool FROM_BF16>
__global__ __launch_bounds__(512, 4) void loss_kernel(const void* __restrict__ src,
                                                      float* __restrict__ accum) {
  // triangular decode: block b -> (tr, tc), tr <= tc
  const int b = blockIdx.x;
  int tr = (int)((2 * NTILE + 1 - sqrtf((float)((2 * NTILE + 1) * (2 * NTILE + 1)) - 8.0f * (float)b)) * 0.5f);
  while (tr * NTILE - tr * (tr - 1) / 2 > b) --tr;
  while ((tr + 1) * NTILE - (tr + 1) * tr / 2 <= b) ++tr;
  const int tc = tr + (b - (tr * NTILE - tr * (tr - 1) / 2));

  __shared__ alignas(16) unsigned short As[128 * 128];  // 32 KiB
  __shared__ alignas(16) unsigned short Bs[128 * 128];  // 32 KiB
  __shared__ float red[8];
  const int tid = threadIdx.x;

  if constexpr (FROM_BF16) {
    const unsigned char* srcA = (const unsigned char*)src + (size_t)tr * 32768;
    const unsigned char* srcB = (const unsigned char*)src + (size_t)tc * 32768;
#pragma unroll
    for (int it = 0; it < 4; ++it) {
      int p = (it * 512 + tid) * 16;
      int g = p ^ (((p >> 8) & 7) << 4);
      __builtin_amdgcn_global_load_lds((gptr_t)(srcA + g),
                                       (lptr_t)((unsigned char*)As + p), 16, 0, 0);
      __builtin_amdgcn_global_load_lds((gptr_t)(srcB + g),
                                       (lptr_t)((unsigned char*)Bs + p), 16, 0, 0);
    }
  } else {
    const float4* srcA4 = (const float4*)((const float*)src + (size_t)tr * 128 * 128);
    const float4* srcB4 = (const float4*)((const float*)src + (size_t)tc * 128 * 128);
#pragma unroll
    for (int it = 0; it < 8; ++it) {
      int idx = it * 512 + tid;  // float4 index within slab [0,4096)
      int L = idx * 8;
      int swz = L ^ (((L >> 8) & 7) << 4);
      float4 a = srcA4[idx];
      ushort4 oa = {f2bf(a.x * SQRT_LOG2E), f2bf(a.y * SQRT_LOG2E),
                    f2bf(a.z * SQRT_LOG2E), f2bf(a.w * SQRT_LOG2E)};
      *reinterpret_cast<ushort4*>((unsigned char*)As + swz) = oa;
      float4 bb = srcB4[idx];
      ushort4 ob = {f2bf(bb.x * SQRT_LOG2E), f2bf(bb.y * SQRT_LOG2E),
                    f2bf(bb.z * SQRT_LOG2E), f2bf(bb.w * SQRT_LOG2E)};
      *reinterpret_cast<ushort4*>((unsigned char*)Bs + swz) = ob;
    }
  }
  __syncthreads();

  const int wid = tid >> 6;
  const int lane = tid & 63;
  const int wm = wid >> 2, wn = wid & 3;  // 2x4 waves: 64x32 output each
  const int lrow = lane & 15;
  const int kgrp = lane >> 4;

  f32x4 acc[4][2];
#pragma unroll
  for (int a = 0; a < 4; ++a)
#pragma unroll
    for (int c = 0; c < 2; ++c) acc[a][c] = (f32x4){0.f, 0.f, 0.f, 0.f};

#pragma unroll
  for (int ks = 0; ks < 4; ++ks) {  // K = 128 = 4 * 32
    bf16x8 af[4], bfr[2];
#pragma unroll
    for (int f = 0; f < 4; ++f) {
      int ar = wm * 64 + f * 16 + lrow;
      int ab = (ar * 256 + ks * 64 + kgrp * 16) ^ ((ar & 7) << 4);
      af[f] = *reinterpret_cast<const bf16x8*>((const unsigned char*)As + ab);
    }
#pragma unroll
    for (int f = 0; f < 2; ++f) {
      int br = wn * 32 + f * 16 + lrow;
      int bb = (br * 256 + ks * 64 + kgrp * 16) ^ ((br & 7) << 4);
      bfr[f] = *reinterpret_cast<const bf16x8*>((const unsigned char*)Bs + bb);
    }
#pragma unroll
    for (int fm = 0; fm < 4; ++fm)
#pragma unroll
      for (int fn = 0; fn < 2; ++fn)
        acc[fm][fn] = __builtin_amdgcn_mfma_f32_16x16x32_bf16(af[fm], bfr[fn], acc[fm][fn], 0, 0, 0);
  }

  // Epilogue in log2 domain. C/D layout: col = lane&15, row = (lane>>4)*4+reg.
  float sm = 0.f, sp = 0.f;
  if (tr == tc) {
#pragma unroll
    for (int fm = 0; fm < 4; ++fm)
#pragma unroll
      for (int fn = 0; fn < 2; ++fn)
#pragma unroll
        for (int r = 0; r < 4; ++r) {
          float v = acc[fm][fn][r];
          int il = wm * 64 + fm * 16 + kgrp * 4 + r;
          int jl = wn * 32 + fn * 16 + lrow;
          if (il == jl) v = -v;
          sm += fmaxf(v, 0.f);
          float u = EXP2F(-fabsf(v));
          sp = fmaf(u, fmaf(u, fmaf(u, PC2, PC1), PC0), sp);
        }
  } else {
#pragma unroll
    for (int fm = 0; fm < 4; ++fm)
#pragma unroll
      for (int fn = 0; fn < 2; ++fn)
#pragma unroll
        for (int r = 0; r < 4; ++r) {
          float v = acc[fm][fn][r];
          sm += fmaxf(v, 0.f);
          float u = EXP2F(-fabsf(v));
          sp = fmaf(u, fmaf(u, fmaf(u, PC2, PC1), PC0), sp);
        }
    sm *= 2.f;  // symmetric twin tile
    sp *= 2.f;
  }

  float lsum = sm + sp;
#pragma unroll
  for (int off = 32; off > 0; off >>= 1) lsum += __shfl_down(lsum, off);

  if (lane == 0) red[wid] = lsum;
  __syncthreads();
  if (tid == 0) {
    float t = red[0] + red[1] + red[2] + red[3] + red[4] + red[5] + red[6] + red[7];
    atomicAdd(accum, t);
  }
}

__global__ void finalize_kernel(const float* __restrict__ accum, float* __restrict__ out) {
  // accum is in log2 units: loss = ln2 * (accum/N + 1)
  out[0] = LN2F * (accum[0] * (1.0f / (float)N_DOCS) + 1.0f);
}

extern "C" void kernel_launch(void* const* d_in, const int* in_sizes, int n_in,
                              void* d_out, int out_size, void* d_ws, size_t ws_size,
                              hipStream_t stream) {
  const float* E = (const float*)d_in[0];
  float* out = (float*)d_out;
  float* accum = (float*)d_ws;  // 4 B

  const size_t need = 256 + (size_t)N_DOCS * DIM * sizeof(unsigned short);  // ~4 MiB
  if (ws_size >= need) {
    unsigned short* ebf = (unsigned short*)((char*)d_ws + 256);
    cast_kernel<<<(N_DOCS * DIM / 4) / 256, 256, 0, stream>>>(E, ebf, accum);
    loss_kernel<true><<<NTRI, 512, 0, stream>>>(ebf, accum);
  } else {
    (void)hipMemsetAsync(accum, 0, sizeof(float), stream);
    loss_kernel<false><<<NTRI, 512, 0, stream>>>(E, accum);
  }
  finalize_kernel<<<1, 1, 0, stream>>>(accum, out);
}